// Round 4
// baseline (4620.750 us; speedup 1.0000x reference)
//
#include <hip/hip_runtime.h>

constexpr int N = 100000;
constexpr int E = 1600000;
constexpr int ROWS = 64;   // rows staged per block in gemm kernels

// ================= CSR build (dst-major) =================
__global__ __launch_bounds__(256) void hist_kernel(const int* __restrict__ ei,
                                                   int* __restrict__ deg) {
    for (int e = blockIdx.x * 256 + threadIdx.x; e < E; e += gridDim.x * 256)
        atomicAdd(&deg[ei[E + e]], 1);
}

__global__ __launch_bounds__(256) void scan_block(const int* __restrict__ deg,
                                                  int* __restrict__ off,
                                                  int* __restrict__ bsum) {
    __shared__ int tmp[256];
    int i = blockIdx.x * 256 + threadIdx.x;
    int v = (i < N) ? deg[i] : 0;
    tmp[threadIdx.x] = v;
    __syncthreads();
    for (int d = 1; d < 256; d <<= 1) {
        int t = (threadIdx.x >= d) ? tmp[threadIdx.x - d] : 0;
        __syncthreads();
        tmp[threadIdx.x] += t;
        __syncthreads();
    }
    if (i < N) off[i] = tmp[threadIdx.x] - v;
    if (threadIdx.x == 255) bsum[blockIdx.x] = tmp[255];
}

__global__ void scan_bsum(int* __restrict__ bsum, int nb) {
    __shared__ int tmp[512];
    int t = threadIdx.x;
    if (t < nb) tmp[t] = bsum[t];
    __syncthreads();
    if (t == 0) {
        int acc = 0;
        for (int b = 0; b < nb; ++b) { int x = tmp[b]; tmp[b] = acc; acc += x; }
    }
    __syncthreads();
    if (t < nb) bsum[t] = tmp[t];
}

__global__ __launch_bounds__(256) void scan_add(int* __restrict__ off,
                                                const int* __restrict__ bsum,
                                                int* __restrict__ cursor) {
    int i = blockIdx.x * 256 + threadIdx.x;
    if (i < N) { int v = off[i] + bsum[blockIdx.x]; off[i] = v; cursor[i] = v; }
}

__global__ __launch_bounds__(256) void fill_kernel(const int* __restrict__ ei,
                                                   int* __restrict__ cursor,
                                                   int* __restrict__ csr) {
    for (int e = blockIdx.x * 256 + threadIdx.x; e < E; e += gridDim.x * 256) {
        int pos = atomicAdd(&cursor[ei[E + e]], 1);
        csr[pos] = ei[e];
    }
}

// ================= pull aggregation, 8 floats/thread =================
template<int C, bool ADD>
__global__ __launch_bounds__(256) void pull8(const float* __restrict__ feat,
                                             const int* __restrict__ off,
                                             const int* __restrict__ csr,
                                             float* __restrict__ out) {
    constexpr int TPN = C / 8;
    int t = blockIdx.x * 256 + threadIdx.x;
    int n = t / TPN, g = t % TPN;
    if (n >= N) return;
    int beg = off[n];
    int end = (n == N - 1) ? E : off[n + 1];
    float4 a0 = {0.f,0.f,0.f,0.f}, a1 = {0.f,0.f,0.f,0.f};
    for (int j = beg; j < end; ++j) {
        int s = csr[j];
        const float* p = feat + (size_t)s * C + g * 8;
        float4 v0 = *(const float4*)p;
        float4 v1 = *(const float4*)(p + 4);
        a0.x += v0.x; a0.y += v0.y; a0.z += v0.z; a0.w += v0.w;
        a1.x += v1.x; a1.y += v1.y; a1.z += v1.z; a1.w += v1.w;
    }
    float* op = out + (size_t)n * C + g * 8;
    if (ADD) {
        float4 b0 = *(const float4*)op, b1 = *(const float4*)(op + 4);
        a0.x += b0.x; a0.y += b0.y; a0.z += b0.z; a0.w += b0.w;
        a1.x += b1.x; a1.y += b1.y; a1.z += b1.z; a1.w += b1.w;
    }
    *(float4*)op = a0;
    *(float4*)(op + 4) = a1;
}

// ================= LDS-staged GEMM =================
// Block: 256 threads = 64 rows x 4 parts. Rows staged once in LDS (coalesced),
// thread (rl=t>>2, part=t&3) computes M/4 columns. Weight streams: 4 distinct
// L1-broadcast streams per wave. Pad K+4 keeps ds_read_b128 conflicts <=2-way.
template<int K, int M, bool RELU, bool DUAL>
__global__ __launch_bounds__(256) void gemm_lds(
    const float* __restrict__ in, const float* __restrict__ W,
    const float* __restrict__ bias,
    const float* __restrict__ in2, const float* __restrict__ W2,
    float* __restrict__ out)
{
    constexpr int STR = K + 4;
    constexpr int MC  = M / 4;
    __shared__ float sa[(DUAL ? 2 : 1) * ROWS * STR];

    const int rowbase = blockIdx.x * ROWS;
    {
        constexpr int NV = ROWS * (K / 4);
        for (int v = threadIdx.x; v < NV; v += 256) {
            int r = v / (K / 4), c = v % (K / 4);
            int rr = rowbase + r;
            float4 val = {0.f,0.f,0.f,0.f};
            if (rr < N) val = *(const float4*)(in + (size_t)rr * K + c * 4);
            *(float4*)(&sa[r * STR + c * 4]) = val;
            if (DUAL) {
                float4 v2 = {0.f,0.f,0.f,0.f};
                if (rr < N) v2 = *(const float4*)(in2 + (size_t)rr * K + c * 4);
                *(float4*)(&sa[ROWS * STR + r * STR + c * 4]) = v2;
            }
        }
    }
    __syncthreads();

    const int part = threadIdx.x & 3;
    const int rl   = threadIdx.x >> 2;
    const int row  = rowbase + rl;
    if (row >= N) return;                 // no further barriers below
    const float* arow  = &sa[rl * STR];
    const float* arow2 = &sa[ROWS * STR + rl * STR];
    float* op = out + (size_t)row * M;

    #pragma unroll 1
    for (int mg = 0; mg < MC / 4; ++mg) {
        const int col0 = part * MC + mg * 4;
        float acc0, acc1, acc2, acc3;
        if (bias) {
            acc0 = bias[col0+0]; acc1 = bias[col0+1];
            acc2 = bias[col0+2]; acc3 = bias[col0+3];
        } else {
            acc0 = acc1 = acc2 = acc3 = 0.f;
        }
        {
            const float* w0 = W + (size_t)col0 * K;
            const float* w1 = w0 + K;
            const float* w2 = w0 + 2 * K;
            const float* w3 = w0 + 3 * K;
            #pragma unroll 4
            for (int i = 0; i < K; i += 4) {
                float4 av = *(const float4*)(arow + i);
                float4 q0 = *(const float4*)(w0 + i);
                float4 q1 = *(const float4*)(w1 + i);
                float4 q2 = *(const float4*)(w2 + i);
                float4 q3 = *(const float4*)(w3 + i);
                acc0 = fmaf(av.x,q0.x,acc0); acc0 = fmaf(av.y,q0.y,acc0);
                acc0 = fmaf(av.z,q0.z,acc0); acc0 = fmaf(av.w,q0.w,acc0);
                acc1 = fmaf(av.x,q1.x,acc1); acc1 = fmaf(av.y,q1.y,acc1);
                acc1 = fmaf(av.z,q1.z,acc1); acc1 = fmaf(av.w,q1.w,acc1);
                acc2 = fmaf(av.x,q2.x,acc2); acc2 = fmaf(av.y,q2.y,acc2);
                acc2 = fmaf(av.z,q2.z,acc2); acc2 = fmaf(av.w,q2.w,acc2);
                acc3 = fmaf(av.x,q3.x,acc3); acc3 = fmaf(av.y,q3.y,acc3);
                acc3 = fmaf(av.z,q3.z,acc3); acc3 = fmaf(av.w,q3.w,acc3);
            }
        }
        if (DUAL) {
            const float* u0 = W2 + (size_t)col0 * K;
            const float* u1 = u0 + K;
            const float* u2 = u0 + 2 * K;
            const float* u3 = u0 + 3 * K;
            #pragma unroll 4
            for (int i = 0; i < K; i += 4) {
                float4 av = *(const float4*)(arow2 + i);
                float4 q0 = *(const float4*)(u0 + i);
                float4 q1 = *(const float4*)(u1 + i);
                float4 q2 = *(const float4*)(u2 + i);
                float4 q3 = *(const float4*)(u3 + i);
                acc0 = fmaf(av.x,q0.x,acc0); acc0 = fmaf(av.y,q0.y,acc0);
                acc0 = fmaf(av.z,q0.z,acc0); acc0 = fmaf(av.w,q0.w,acc0);
                acc1 = fmaf(av.x,q1.x,acc1); acc1 = fmaf(av.y,q1.y,acc1);
                acc1 = fmaf(av.z,q1.z,acc1); acc1 = fmaf(av.w,q1.w,acc1);
                acc2 = fmaf(av.x,q2.x,acc2); acc2 = fmaf(av.y,q2.y,acc2);
                acc2 = fmaf(av.z,q2.z,acc2); acc2 = fmaf(av.w,q2.w,acc2);
                acc3 = fmaf(av.x,q3.x,acc3); acc3 = fmaf(av.y,q3.y,acc3);
                acc3 = fmaf(av.z,q3.z,acc3); acc3 = fmaf(av.w,q3.w,acc3);
            }
        }
        if (RELU) {
            acc0 = fmaxf(acc0, 0.f); acc1 = fmaxf(acc1, 0.f);
            acc2 = fmaxf(acc2, 0.f); acc3 = fmaxf(acc3, 0.f);
        }
        float4 r4; r4.x = acc0; r4.y = acc1; r4.z = acc2; r4.w = acc3;
        *(float4*)(op + col0) = r4;
    }
}

// ================= fused projection + message pre-transform (LDS) =================
// out = relu(in@Wp^T + bp) @ Wl^T, H = K (128). Stage1 -> registers; H swapped
// back into the same LDS buffer; stage2 multiplies by Wl. No early returns
// (3 barriers) -- stores guarded instead.
template<int K, int M2>
__global__ __launch_bounds__(256) void gemm_proj2(
    const float* __restrict__ in, const float* __restrict__ Wp,
    const float* __restrict__ bp, const float* __restrict__ Wl,
    float* __restrict__ out)
{
    constexpr int STR = K + 4;
    constexpr int MC  = K / 4;    // stage-1 cols per thread (H == K)
    constexpr int MC2 = M2 / 4;
    __shared__ float sa[ROWS * STR];

    const int rowbase = blockIdx.x * ROWS;
    {
        constexpr int NV = ROWS * (K / 4);
        for (int v = threadIdx.x; v < NV; v += 256) {
            int r = v / (K / 4), c = v % (K / 4);
            int rr = rowbase + r;
            float4 val = {0.f,0.f,0.f,0.f};
            if (rr < N) val = *(const float4*)(in + (size_t)rr * K + c * 4);
            *(float4*)(&sa[r * STR + c * 4]) = val;
        }
    }
    __syncthreads();

    const int part = threadIdx.x & 3;
    const int rl   = threadIdx.x >> 2;
    const int row  = rowbase + rl;
    const float* arow = &sa[rl * STR];

    float h[MC];
    #pragma unroll 1
    for (int mg = 0; mg < MC / 4; ++mg) {
        const int col0 = part * MC + mg * 4;
        float acc0 = bp[col0+0], acc1 = bp[col0+1], acc2 = bp[col0+2], acc3 = bp[col0+3];
        const float* w0 = Wp + (size_t)col0 * K;
        const float* w1 = w0 + K;
        const float* w2 = w0 + 2 * K;
        const float* w3 = w0 + 3 * K;
        #pragma unroll 4
        for (int i = 0; i < K; i += 4) {
            float4 av = *(const float4*)(arow + i);
            float4 q0 = *(const float4*)(w0 + i);
            float4 q1 = *(const float4*)(w1 + i);
            float4 q2 = *(const float4*)(w2 + i);
            float4 q3 = *(const float4*)(w3 + i);
            acc0 = fmaf(av.x,q0.x,acc0); acc0 = fmaf(av.y,q0.y,acc0);
            acc0 = fmaf(av.z,q0.z,acc0); acc0 = fmaf(av.w,q0.w,acc0);
            acc1 = fmaf(av.x,q1.x,acc1); acc1 = fmaf(av.y,q1.y,acc1);
            acc1 = fmaf(av.z,q1.z,acc1); acc1 = fmaf(av.w,q1.w,acc1);
            acc2 = fmaf(av.x,q2.x,acc2); acc2 = fmaf(av.y,q2.y,acc2);
            acc2 = fmaf(av.z,q2.z,acc2); acc2 = fmaf(av.w,q2.w,acc2);
            acc3 = fmaf(av.x,q3.x,acc3); acc3 = fmaf(av.y,q3.y,acc3);
            acc3 = fmaf(av.z,q3.z,acc3); acc3 = fmaf(av.w,q3.w,acc3);
        }
        h[mg*4+0] = fmaxf(acc0, 0.f);
        h[mg*4+1] = fmaxf(acc1, 0.f);
        h[mg*4+2] = fmaxf(acc2, 0.f);
        h[mg*4+3] = fmaxf(acc3, 0.f);
    }
    __syncthreads();   // all input-row reads done; reuse sa for H
    #pragma unroll
    for (int j = 0; j < MC; j += 4)
        *(float4*)(&sa[rl * STR + part * MC + j]) = make_float4(h[j],h[j+1],h[j+2],h[j+3]);
    __syncthreads();

    float* op = out + (size_t)row * M2;
    #pragma unroll 1
    for (int mg = 0; mg < MC2 / 4; ++mg) {
        const int col0 = part * MC2 + mg * 4;
        float acc0 = 0.f, acc1 = 0.f, acc2 = 0.f, acc3 = 0.f;
        const float* w0 = Wl + (size_t)col0 * K;
        const float* w1 = w0 + K;
        const float* w2 = w0 + 2 * K;
        const float* w3 = w0 + 3 * K;
        #pragma unroll 4
        for (int i = 0; i < K; i += 4) {
            float4 av = *(const float4*)(arow + i);
            float4 q0 = *(const float4*)(w0 + i);
            float4 q1 = *(const float4*)(w1 + i);
            float4 q2 = *(const float4*)(w2 + i);
            float4 q3 = *(const float4*)(w3 + i);
            acc0 = fmaf(av.x,q0.x,acc0); acc0 = fmaf(av.y,q0.y,acc0);
            acc0 = fmaf(av.z,q0.z,acc0); acc0 = fmaf(av.w,q0.w,acc0);
            acc1 = fmaf(av.x,q1.x,acc1); acc1 = fmaf(av.y,q1.y,acc1);
            acc1 = fmaf(av.z,q1.z,acc1); acc1 = fmaf(av.w,q1.w,acc1);
            acc2 = fmaf(av.x,q2.x,acc2); acc2 = fmaf(av.y,q2.y,acc2);
            acc2 = fmaf(av.z,q2.z,acc2); acc2 = fmaf(av.w,q2.w,acc2);
            acc3 = fmaf(av.x,q3.x,acc3); acc3 = fmaf(av.y,q3.y,acc3);
            acc3 = fmaf(av.z,q3.z,acc3); acc3 = fmaf(av.w,q3.w,acc3);
        }
        if (row < N) {
            float4 r4; r4.x = acc0; r4.y = acc1; r4.z = acc2; r4.w = acc3;
            *(float4*)(op + col0) = r4;
        }
    }
}

extern "C" void kernel_launch(void* const* d_in, const int* in_sizes, int n_in,
                              void* d_out, int out_size, void* d_ws, size_t ws_size,
                              hipStream_t stream)
{
    const float* x   = (const float*)d_in[0];
    const int*   ei  = (const int*)d_in[1];
    const float *e1_Wp=(const float*)d_in[2],  *e1_bp=(const float*)d_in[3],
                *e1_Wl=(const float*)d_in[4],  *e1_bl=(const float*)d_in[5],
                *e1_Wr=(const float*)d_in[6];
    const float *e2_Wp=(const float*)d_in[7],  *e2_bp=(const float*)d_in[8],
                *e2_Wl=(const float*)d_in[9],  *e2_bl=(const float*)d_in[10],
                *e2_Wr=(const float*)d_in[11];
    const float *d1_Wp=(const float*)d_in[12], *d1_bp=(const float*)d_in[13],
                *d1_Wl=(const float*)d_in[14], *d1_bl=(const float*)d_in[15],
                *d1_Wr=(const float*)d_in[16];
    const float *d2_Wp=(const float*)d_in[17], *d2_bp=(const float*)d_in[18],
                *d2_Wl=(const float*)d_in[19], *d2_bl=(const float*)d_in[20],
                *d2_Wr=(const float*)d_in[21];

    // ---- workspace ----
    int* off  = (int*)d_ws;                     // N (persistent)
    int* csr  = off + N;                        // E (persistent)
    float* R1 = (float*)(csr + E);              // [N][128] layer output
    float* R2 = R1 + (size_t)N * 128;           // [N][128] conv1 scratch
    float* R3 = R2 + (size_t)N * 128;           // [N][64]  msgs / agg
    // CSR-build temporaries alias R3 (done before R3's first float use)
    int* deg    = (int*)R3;
    int* cursor = deg + N;
    int* bsum   = cursor + N;

    float* xrec = (float*)d_out;                // [N][64]
    float* z    = xrec + (size_t)N * 64;        // [N][32]

    const int GB  = (N + 255) / 256;            // 391 (scan grids)
    const int GR  = (N + ROWS - 1) / ROWS;      // 1563 (gemm grids)

    // ---- CSR build ----
    hipMemsetAsync(deg, 0, N * sizeof(int), stream);
    hist_kernel<<<2048, 256, 0, stream>>>(ei, deg);
    scan_block<<<GB, 256, 0, stream>>>(deg, off, bsum);
    scan_bsum<<<1, 512, 0, stream>>>(bsum, GB);
    scan_add<<<GB, 256, 0, stream>>>(off, bsum, cursor);
    fill_kernel<<<2048, 256, 0, stream>>>(ei, cursor, csr);

    float* AP1 = R2;                    // conv1 messages [N][64]
    float* B1  = R2 + (size_t)N * 64;   // conv1 agg [N][64]
    float* AP2 = R3;                    // conv2/conv3 msgs [N][32]
    float* B3  = R3 + (size_t)N * 32;   // conv3 agg [N][32]
    float* AP4 = R3;                    // conv4 msgs [N][64]

    // ---- conv1 (e1): 64 -> 128, relu ----
    gemm_lds<64,64,true,false><<<GR, 256, 0, stream>>>(x, e1_Wp, e1_bp, nullptr, nullptr, AP1);
    pull8<64,false><<<(N*8 + 255)/256, 256, 0, stream>>>(AP1, off, csr, B1);
    gemm_lds<64,128,true,true><<<GR, 256, 0, stream>>>(B1, e1_Wl, e1_bl, x, e1_Wr, R1);

    // ---- conv2 (e2): 128 -> 32 = z ----
    gemm_lds<128,32,false,false><<<GR, 256, 0, stream>>>(R1, e2_Wr, e2_bl, nullptr, nullptr, z);
    gemm_proj2<128,32><<<GR, 256, 0, stream>>>(R1, e2_Wp, e2_bp, e2_Wl, AP2);
    pull8<32,true><<<(N*4 + 255)/256, 256, 0, stream>>>(AP2, off, csr, z);

    // ---- conv3 (d1): 32 -> 128, relu ----
    gemm_lds<32,32,true,false><<<GR, 256, 0, stream>>>(z, d1_Wp, d1_bp, nullptr, nullptr, AP2);
    pull8<32,false><<<(N*4 + 255)/256, 256, 0, stream>>>(AP2, off, csr, B3);
    gemm_lds<32,128,true,true><<<GR, 256, 0, stream>>>(B3, d1_Wl, d1_bl, z, d1_Wr, R1);

    // ---- conv4 (d2): 128 -> 64 = x_rec ----
    gemm_lds<128,64,false,false><<<GR, 256, 0, stream>>>(R1, d2_Wr, d2_bl, nullptr, nullptr, xrec);
    gemm_proj2<128,64><<<GR, 256, 0, stream>>>(R1, d2_Wp, d2_bp, d2_Wl, AP4);
    pull8<64,true><<<(N*8 + 255)/256, 256, 0, stream>>>(AP4, off, csr, xrec);
}

// Round 5
// 1108.828 us; speedup vs baseline: 4.1672x; 4.1672x over previous
//
#include <hip/hip_runtime.h>

constexpr int N = 100000;
constexpr int E = 1600000;

// ================= CSR build (dst-major) =================
__global__ __launch_bounds__(256) void hist_kernel(const int* __restrict__ ei,
                                                   int* __restrict__ deg) {
    for (int e = blockIdx.x * 256 + threadIdx.x; e < E; e += gridDim.x * 256)
        atomicAdd(&deg[ei[E + e]], 1);
}

__global__ __launch_bounds__(256) void scan_block(const int* __restrict__ deg,
                                                  int* __restrict__ off,
                                                  int* __restrict__ bsum) {
    __shared__ int tmp[256];
    int i = blockIdx.x * 256 + threadIdx.x;
    int v = (i < N) ? deg[i] : 0;
    tmp[threadIdx.x] = v;
    __syncthreads();
    for (int d = 1; d < 256; d <<= 1) {
        int t = (threadIdx.x >= d) ? tmp[threadIdx.x - d] : 0;
        __syncthreads();
        tmp[threadIdx.x] += t;
        __syncthreads();
    }
    if (i < N) off[i] = tmp[threadIdx.x] - v;
    if (threadIdx.x == 255) bsum[blockIdx.x] = tmp[255];
}

__global__ void scan_bsum(int* __restrict__ bsum, int nb) {
    __shared__ int tmp[512];
    int t = threadIdx.x;
    if (t < nb) tmp[t] = bsum[t];
    __syncthreads();
    if (t == 0) {
        int acc = 0;
        for (int b = 0; b < nb; ++b) { int x = tmp[b]; tmp[b] = acc; acc += x; }
    }
    __syncthreads();
    if (t < nb) bsum[t] = tmp[t];
}

__global__ __launch_bounds__(256) void scan_add(int* __restrict__ off,
                                                const int* __restrict__ bsum,
                                                int* __restrict__ cursor) {
    int i = blockIdx.x * 256 + threadIdx.x;
    if (i < N) { int v = off[i] + bsum[blockIdx.x]; off[i] = v; cursor[i] = v; }
}

__global__ __launch_bounds__(256) void fill_kernel(const int* __restrict__ ei,
                                                   int* __restrict__ cursor,
                                                   int* __restrict__ csr) {
    for (int e = blockIdx.x * 256 + threadIdx.x; e < E; e += gridDim.x * 256) {
        int pos = atomicAdd(&cursor[ei[E + e]], 1);
        csr[pos] = ei[e];
    }
}

// ================= pull aggregation, 8 floats/thread =================
template<int C, bool ADD>
__global__ __launch_bounds__(256) void pull8(const float* __restrict__ feat,
                                             const int* __restrict__ off,
                                             const int* __restrict__ csr,
                                             float* __restrict__ out) {
    constexpr int TPN = C / 8;
    int t = blockIdx.x * 256 + threadIdx.x;
    int n = t / TPN, g = t % TPN;
    if (n >= N) return;
    int beg = off[n];
    int end = (n == N - 1) ? E : off[n + 1];
    float4 a0 = {0.f,0.f,0.f,0.f}, a1 = {0.f,0.f,0.f,0.f};
    for (int j = beg; j < end; ++j) {
        int s = csr[j];
        const float* p = feat + (size_t)s * C + g * 8;
        float4 v0 = *(const float4*)p;
        float4 v1 = *(const float4*)(p + 4);
        a0.x += v0.x; a0.y += v0.y; a0.z += v0.z; a0.w += v0.w;
        a1.x += v1.x; a1.y += v1.y; a1.z += v1.z; a1.w += v1.w;
    }
    float* op = out + (size_t)n * C + g * 8;
    if (ADD) {
        float4 b0 = *(const float4*)op, b1 = *(const float4*)(op + 4);
        a0.x += b0.x; a0.y += b0.y; a0.z += b0.z; a0.w += b0.w;
        a1.x += b1.x; a1.y += b1.y; a1.z += b1.z; a1.w += b1.w;
    }
    *(float4*)op = a0;
    *(float4*)(op + 4) = a1;
}

// ================= wave-split row-per-thread GEMM =================
// Block = 256 threads = 4 waves. lane (0..63) -> row, wave -> column part.
// part goes through readfirstlane so it is SGPR-provably uniform: weight
// streams stay s_load broadcasts (the property R3 accidentally destroyed).
// The 4 waves share 64 rows on the SAME CU -> redundant row reads are L1 hits,
// not cross-XCD HBM traffic (R2's failure mode).
template<int K, int M, bool RELU, bool DUAL>
__global__ __launch_bounds__(256) void gemm_wave(
    const float* __restrict__ in, const float* __restrict__ W,
    const float* __restrict__ bias,
    const float* __restrict__ in2, const float* __restrict__ W2,
    float* __restrict__ out)
{
    constexpr int MC = M / 4;
    const int lane = threadIdx.x & 63;
    const int part = __builtin_amdgcn_readfirstlane(threadIdx.x >> 6);
    const int row  = blockIdx.x * 64 + lane;
    if (row >= N) return;

    float a[K];
    {
        const float* ip = in + (size_t)row * K;
        #pragma unroll
        for (int i = 0; i < K; i += 4) {
            float4 v = *(const float4*)(ip + i);
            a[i] = v.x; a[i+1] = v.y; a[i+2] = v.z; a[i+3] = v.w;
        }
    }
    float a2[DUAL ? K : 4];
    if (DUAL) {
        const float* ip2 = in2 + (size_t)row * K;
        #pragma unroll
        for (int i = 0; i < K; i += 4) {
            float4 v = *(const float4*)(ip2 + i);
            a2[i] = v.x; a2[i+1] = v.y; a2[i+2] = v.z; a2[i+3] = v.w;
        }
    }

    const float* Wb  = W + (size_t)part * MC * K;
    const float* W2b = DUAL ? W2 + (size_t)part * MC * K : nullptr;
    const float* bb  = bias ? bias + part * MC : nullptr;
    float* op = out + (size_t)row * M + part * MC;

    #pragma unroll 1
    for (int mg = 0; mg < MC / 4; ++mg) {
        float acc0, acc1, acc2, acc3;
        if (bb) {
            acc0 = bb[mg*4+0]; acc1 = bb[mg*4+1];
            acc2 = bb[mg*4+2]; acc3 = bb[mg*4+3];
        } else {
            acc0 = acc1 = acc2 = acc3 = 0.f;
        }
        {
            const float* w0 = Wb + (size_t)(mg*4+0) * K;
            const float* w1 = w0 + K;
            const float* w2 = w0 + 2*K;
            const float* w3 = w0 + 3*K;
            #pragma unroll
            for (int i = 0; i < K; ++i) {
                float av = a[i];
                acc0 = fmaf(av, w0[i], acc0);
                acc1 = fmaf(av, w1[i], acc1);
                acc2 = fmaf(av, w2[i], acc2);
                acc3 = fmaf(av, w3[i], acc3);
            }
        }
        if (DUAL) {
            const float* u0 = W2b + (size_t)(mg*4+0) * K;
            const float* u1 = u0 + K;
            const float* u2 = u0 + 2*K;
            const float* u3 = u0 + 3*K;
            #pragma unroll
            for (int i = 0; i < K; ++i) {
                float av = a2[i];
                acc0 = fmaf(av, u0[i], acc0);
                acc1 = fmaf(av, u1[i], acc1);
                acc2 = fmaf(av, u2[i], acc2);
                acc3 = fmaf(av, u3[i], acc3);
            }
        }
        if (RELU) {
            acc0 = fmaxf(acc0, 0.f); acc1 = fmaxf(acc1, 0.f);
            acc2 = fmaxf(acc2, 0.f); acc3 = fmaxf(acc3, 0.f);
        }
        float4 r; r.x = acc0; r.y = acc1; r.z = acc2; r.w = acc3;
        *(float4*)(op + mg*4) = r;
    }
}

extern "C" void kernel_launch(void* const* d_in, const int* in_sizes, int n_in,
                              void* d_out, int out_size, void* d_ws, size_t ws_size,
                              hipStream_t stream)
{
    const float* x   = (const float*)d_in[0];
    const int*   ei  = (const int*)d_in[1];
    const float *e1_Wp=(const float*)d_in[2],  *e1_bp=(const float*)d_in[3],
                *e1_Wl=(const float*)d_in[4],  *e1_bl=(const float*)d_in[5],
                *e1_Wr=(const float*)d_in[6];
    const float *e2_Wp=(const float*)d_in[7],  *e2_bp=(const float*)d_in[8],
                *e2_Wl=(const float*)d_in[9],  *e2_bl=(const float*)d_in[10],
                *e2_Wr=(const float*)d_in[11];
    const float *d1_Wp=(const float*)d_in[12], *d1_bp=(const float*)d_in[13],
                *d1_Wl=(const float*)d_in[14], *d1_bl=(const float*)d_in[15],
                *d1_Wr=(const float*)d_in[16];
    const float *d2_Wp=(const float*)d_in[17], *d2_bp=(const float*)d_in[18],
                *d2_Wl=(const float*)d_in[19], *d2_bl=(const float*)d_in[20],
                *d2_Wr=(const float*)d_in[21];

    // ---- workspace ----
    int* off  = (int*)d_ws;                     // N (persistent)
    int* csr  = off + N;                        // E (persistent)
    float* R1 = (float*)(csr + E);              // [N][128] layer output
    float* R2 = R1 + (size_t)N * 128;           // [N][128] scratch
    float* R3 = R2 + (size_t)N * 128;           // [N][64]  msgs / agg
    // CSR-build temporaries alias R3 (done before R3's first float use)
    int* deg    = (int*)R3;
    int* cursor = deg + N;
    int* bsum   = cursor + N;

    float* xrec = (float*)d_out;                // [N][64]
    float* z    = xrec + (size_t)N * 64;        // [N][32]

    const int GB = (N + 255) / 256;             // 391 (scan grids)
    const int GW = (N + 63) / 64;               // 1563 (gemm grids)

    // ---- CSR build (once; shared by all 4 convs) ----
    hipMemsetAsync(deg, 0, N * sizeof(int), stream);
    hist_kernel<<<2048, 256, 0, stream>>>(ei, deg);
    scan_block<<<GB, 256, 0, stream>>>(deg, off, bsum);
    scan_bsum<<<1, 512, 0, stream>>>(bsum, GB);
    scan_add<<<GB, 256, 0, stream>>>(off, bsum, cursor);
    fill_kernel<<<2048, 256, 0, stream>>>(ei, cursor, csr);

    float* AP1 = R2;                    // conv1 messages [N][64]
    float* B1  = R2 + (size_t)N * 64;   // conv1 agg [N][64]
    float* AP2 = R3;                    // conv2/conv3 msgs [N][32]
    float* B3  = R3 + (size_t)N * 32;   // conv3 agg [N][32]
    float* AP4 = R3;                    // conv4 msgs [N][64]

    // ---- conv1 (e1): 64 -> 128, relu ----
    gemm_wave<64,64,true,false><<<GW, 256, 0, stream>>>(x, e1_Wp, e1_bp, nullptr, nullptr, AP1);
    pull8<64,false><<<(N*8 + 255)/256, 256, 0, stream>>>(AP1, off, csr, B1);
    gemm_wave<64,128,true,true><<<GW, 256, 0, stream>>>(B1, e1_Wl, e1_bl, x, e1_Wr, R1);

    // ---- conv2 (e2): 128 -> 32 = z ----
    gemm_wave<128,32,false,false><<<GW, 256, 0, stream>>>(R1, e2_Wr, e2_bl, nullptr, nullptr, z);
    gemm_wave<128,128,true,false><<<GW, 256, 0, stream>>>(R1, e2_Wp, e2_bp, nullptr, nullptr, R2);
    gemm_wave<128,32,false,false><<<GW, 256, 0, stream>>>(R2, e2_Wl, nullptr, nullptr, nullptr, AP2);
    pull8<32,true><<<(N*4 + 255)/256, 256, 0, stream>>>(AP2, off, csr, z);

    // ---- conv3 (d1): 32 -> 128, relu ----
    gemm_wave<32,32,true,false><<<GW, 256, 0, stream>>>(z, d1_Wp, d1_bp, nullptr, nullptr, AP2);
    pull8<32,false><<<(N*4 + 255)/256, 256, 0, stream>>>(AP2, off, csr, B3);
    gemm_wave<32,128,true,true><<<GW, 256, 0, stream>>>(B3, d1_Wl, d1_bl, z, d1_Wr, R1);

    // ---- conv4 (d2): 128 -> 64 = x_rec ----
    gemm_wave<128,64,false,false><<<GW, 256, 0, stream>>>(R1, d2_Wr, d2_bl, nullptr, nullptr, xrec);
    gemm_wave<128,128,true,false><<<GW, 256, 0, stream>>>(R1, d2_Wp, d2_bp, nullptr, nullptr, R2);
    gemm_wave<128,64,false,false><<<GW, 256, 0, stream>>>(R2, d2_Wl, nullptr, nullptr, nullptr, AP4);
    pull8<64,true><<<(N*8 + 255)/256, 256, 0, stream>>>(AP4, off, csr, xrec);
}

// Round 6
// 725.748 us; speedup vs baseline: 6.3669x; 1.5278x over previous
//
#include <hip/hip_runtime.h>

constexpr int N = 100000;
constexpr int E = 1600000;

// ================= CSR build (dst-major) =================
__global__ __launch_bounds__(256) void hist_kernel(const int* __restrict__ ei,
                                                   int* __restrict__ deg) {
    for (int e = blockIdx.x * 256 + threadIdx.x; e < E; e += gridDim.x * 256)
        atomicAdd(&deg[ei[E + e]], 1);
}

__global__ __launch_bounds__(256) void scan_block(const int* __restrict__ deg,
                                                  int* __restrict__ off,
                                                  int* __restrict__ bsum) {
    __shared__ int tmp[256];
    int i = blockIdx.x * 256 + threadIdx.x;
    int v = (i < N) ? deg[i] : 0;
    tmp[threadIdx.x] = v;
    __syncthreads();
    for (int d = 1; d < 256; d <<= 1) {
        int t = (threadIdx.x >= d) ? tmp[threadIdx.x - d] : 0;
        __syncthreads();
        tmp[threadIdx.x] += t;
        __syncthreads();
    }
    if (i < N) off[i] = tmp[threadIdx.x] - v;
    if (threadIdx.x == 255) bsum[blockIdx.x] = tmp[255];
}

__global__ void scan_bsum(int* __restrict__ bsum, int nb) {
    __shared__ int tmp[512];
    int t = threadIdx.x;
    if (t < nb) tmp[t] = bsum[t];
    __syncthreads();
    if (t == 0) {
        int acc = 0;
        for (int b = 0; b < nb; ++b) { int x = tmp[b]; tmp[b] = acc; acc += x; }
    }
    __syncthreads();
    if (t < nb) bsum[t] = tmp[t];
}

__global__ __launch_bounds__(256) void scan_add(int* __restrict__ off,
                                                const int* __restrict__ bsum,
                                                int* __restrict__ cursor) {
    int i = blockIdx.x * 256 + threadIdx.x;
    if (i < N) { int v = off[i] + bsum[blockIdx.x]; off[i] = v; cursor[i] = v; }
}

__global__ __launch_bounds__(256) void fill_kernel(const int* __restrict__ ei,
                                                   int* __restrict__ cursor,
                                                   int* __restrict__ csr) {
    for (int e = blockIdx.x * 256 + threadIdx.x; e < E; e += gridDim.x * 256) {
        int pos = atomicAdd(&cursor[ei[E + e]], 1);
        csr[pos] = ei[e];
    }
}

// ================= weight transpose: W[M][K] -> Wt[K][M] =================
__global__ __launch_bounds__(256) void transpose_w(const float* __restrict__ W,
                                                   float* __restrict__ Wt,
                                                   int M, int K) {
    int idx = blockIdx.x * 256 + threadIdx.x;
    if (idx < M * K) {
        int m = idx / K, k = idx % K;
        Wt[k * M + m] = W[idx];
    }
}

// ================= pull aggregation, 8 floats/thread =================
template<int C, bool ADD>
__global__ __launch_bounds__(256) void pull8(const float* __restrict__ feat,
                                             const int* __restrict__ off,
                                             const int* __restrict__ csr,
                                             float* __restrict__ out) {
    constexpr int TPN = C / 8;
    int t = blockIdx.x * 256 + threadIdx.x;
    int n = t / TPN, g = t % TPN;
    if (n >= N) return;
    int beg = off[n];
    int end = (n == N - 1) ? E : off[n + 1];
    float4 a0 = {0.f,0.f,0.f,0.f}, a1 = {0.f,0.f,0.f,0.f};
    for (int j = beg; j < end; ++j) {
        int s = csr[j];
        const float* p = feat + (size_t)s * C + g * 8;
        float4 v0 = *(const float4*)p;
        float4 v1 = *(const float4*)(p + 4);
        a0.x += v0.x; a0.y += v0.y; a0.z += v0.z; a0.w += v0.w;
        a1.x += v1.x; a1.y += v1.y; a1.z += v1.z; a1.w += v1.w;
    }
    float* op = out + (size_t)n * C + g * 8;
    if (ADD) {
        float4 b0 = *(const float4*)op, b1 = *(const float4*)(op + 4);
        a0.x += b0.x; a0.y += b0.y; a0.z += b0.z; a0.w += b0.w;
        a1.x += b1.x; a1.y += b1.y; a1.z += b1.z; a1.w += b1.w;
    }
    *(float4*)op = a0;
    *(float4*)(op + 4) = a1;
}

// ================= LDS-tiled GEMM =================
// out[row][:] = act( in[row]@Wt + bias (+ in2[row]@Wt2 if DUAL) ), Wt=[K][M].
// BM=128 rows/block, BK=32, 256 threads as 16x16, thread tile 8 x (M/16).
// A staged transposed -> a[8] = 2 conflict-free ds_read_b128 (16-way bcast
// over tx). B reads are <=2-way-conflict b128 (free). No scalar-uniformity
// assumptions anywhere (R3/R4 lessons). DUAL = virtual-K concat of (in,Wt)
// and (in2,Wt2).
template<int K, int M, bool RELU, bool DUAL>
__global__ __launch_bounds__(256) void gemm_tile(
    const float* __restrict__ in, const float* __restrict__ Wt,
    const float* __restrict__ bias,
    const float* __restrict__ in2, const float* __restrict__ Wt2,
    float* __restrict__ out)
{
    constexpr int BM = 128, BK = 32;
    constexpr int TN  = M / 16;              // 8 / 4 / 2
    constexpr int KT1 = K / BK;              // k-tiles per source
    constexpr int KT  = DUAL ? 2 * KT1 : KT1;
    constexpr int AST = BM + 4;
    constexpr int BST = M + 4;
    __shared__ float As[BK][AST];
    __shared__ float Bs[BK][BST];

    const int tx = threadIdx.x & 15;
    const int ty = threadIdx.x >> 4;
    const int row0 = blockIdx.x * BM;

    float acc[8][TN];
    #pragma unroll
    for (int i = 0; i < 8; ++i)
        #pragma unroll
        for (int j = 0; j < TN; ++j) acc[i][j] = 0.f;

    for (int kt = 0; kt < KT; ++kt) {
        const bool second = DUAL && (kt >= KT1);
        const float* src  = second ? in2 : in;
        const float* wsrc = second ? Wt2 : Wt;
        const int kbase = (second ? kt - KT1 : kt) * BK;

        // ---- stage A transposed: As[k][r] = src[row0+r][kbase+k] ----
        #pragma unroll
        for (int it = 0; it < 4; ++it) {
            int idx = it * 256 + threadIdx.x;   // 0..1023
            int r = idx >> 3, k4 = idx & 7;
            int rr = row0 + r;
            float4 v = {0.f,0.f,0.f,0.f};
            if (rr < N) v = *(const float4*)(src + (size_t)rr * K + kbase + k4 * 4);
            As[k4*4+0][r] = v.x;
            As[k4*4+1][r] = v.y;
            As[k4*4+2][r] = v.z;
            As[k4*4+3][r] = v.w;
        }
        // ---- stage B direct: Bs[k][m] = wsrc[kbase+k][m] ----
        constexpr int BIT = (BK * M / 4) / 256;   // 4/2/1
        #pragma unroll
        for (int it = 0; it < BIT; ++it) {
            int idx = it * 256 + threadIdx.x;
            int k = idx / (M / 4), m4 = idx % (M / 4);
            float4 v = *(const float4*)(wsrc + (size_t)(kbase + k) * M + m4 * 4);
            *(float4*)&Bs[k][m4 * 4] = v;
        }
        __syncthreads();

        #pragma unroll 4
        for (int kk = 0; kk < BK; ++kk) {
            float av[8];
            *(float4*)&av[0] = *(const float4*)&As[kk][ty * 8];
            *(float4*)&av[4] = *(const float4*)&As[kk][ty * 8 + 4];
            float bv[TN];
            if constexpr (TN == 8) {
                *(float4*)&bv[0] = *(const float4*)&Bs[kk][tx * 4];
                *(float4*)&bv[4] = *(const float4*)&Bs[kk][tx * 4 + 64];
            } else if constexpr (TN == 4) {
                *(float4*)&bv[0] = *(const float4*)&Bs[kk][tx * 4];
            } else {
                bv[0] = Bs[kk][tx * 2];
                bv[1] = Bs[kk][tx * 2 + 1];
            }
            #pragma unroll
            for (int i = 0; i < 8; ++i)
                #pragma unroll
                for (int j = 0; j < TN; ++j)
                    acc[i][j] = fmaf(av[i], bv[j], acc[i][j]);
        }
        __syncthreads();
    }

    // ---- epilogue: bias + relu + store ----
    float bb[TN];
    if (bias) {
        if constexpr (TN == 8) {
            *(float4*)&bb[0] = *(const float4*)(bias + tx * 4);
            *(float4*)&bb[4] = *(const float4*)(bias + tx * 4 + 64);
        } else if constexpr (TN == 4) {
            *(float4*)&bb[0] = *(const float4*)(bias + tx * 4);
        } else {
            bb[0] = bias[tx * 2]; bb[1] = bias[tx * 2 + 1];
        }
    } else {
        #pragma unroll
        for (int j = 0; j < TN; ++j) bb[j] = 0.f;
    }

    #pragma unroll
    for (int i = 0; i < 8; ++i) {
        int row = row0 + ty * 8 + i;
        if (row >= N) continue;
        float* op = out + (size_t)row * M;
        if constexpr (TN == 8) {
            float4 r0, r1;
            r0.x = acc[i][0]+bb[0]; r0.y = acc[i][1]+bb[1];
            r0.z = acc[i][2]+bb[2]; r0.w = acc[i][3]+bb[3];
            r1.x = acc[i][4]+bb[4]; r1.y = acc[i][5]+bb[5];
            r1.z = acc[i][6]+bb[6]; r1.w = acc[i][7]+bb[7];
            if (RELU) {
                r0.x=fmaxf(r0.x,0.f); r0.y=fmaxf(r0.y,0.f); r0.z=fmaxf(r0.z,0.f); r0.w=fmaxf(r0.w,0.f);
                r1.x=fmaxf(r1.x,0.f); r1.y=fmaxf(r1.y,0.f); r1.z=fmaxf(r1.z,0.f); r1.w=fmaxf(r1.w,0.f);
            }
            *(float4*)(op + tx * 4) = r0;
            *(float4*)(op + tx * 4 + 64) = r1;
        } else if constexpr (TN == 4) {
            float4 r0;
            r0.x = acc[i][0]+bb[0]; r0.y = acc[i][1]+bb[1];
            r0.z = acc[i][2]+bb[2]; r0.w = acc[i][3]+bb[3];
            if (RELU) {
                r0.x=fmaxf(r0.x,0.f); r0.y=fmaxf(r0.y,0.f); r0.z=fmaxf(r0.z,0.f); r0.w=fmaxf(r0.w,0.f);
            }
            *(float4*)(op + tx * 4) = r0;
        } else {
            float s0 = acc[i][0]+bb[0], s1 = acc[i][1]+bb[1];
            if (RELU) { s0 = fmaxf(s0,0.f); s1 = fmaxf(s1,0.f); }
            float2 r0; r0.x = s0; r0.y = s1;
            *(float2*)(op + tx * 2) = r0;
        }
    }
}

extern "C" void kernel_launch(void* const* d_in, const int* in_sizes, int n_in,
                              void* d_out, int out_size, void* d_ws, size_t ws_size,
                              hipStream_t stream)
{
    const float* x   = (const float*)d_in[0];
    const int*   ei  = (const int*)d_in[1];
    const float *e1_Wp=(const float*)d_in[2],  *e1_bp=(const float*)d_in[3],
                *e1_Wl=(const float*)d_in[4],  *e1_bl=(const float*)d_in[5],
                *e1_Wr=(const float*)d_in[6];
    const float *e2_Wp=(const float*)d_in[7],  *e2_bp=(const float*)d_in[8],
                *e2_Wl=(const float*)d_in[9],  *e2_bl=(const float*)d_in[10],
                *e2_Wr=(const float*)d_in[11];
    const float *d1_Wp=(const float*)d_in[12], *d1_bp=(const float*)d_in[13],
                *d1_Wl=(const float*)d_in[14], *d1_bl=(const float*)d_in[15],
                *d1_Wr=(const float*)d_in[16];
    const float *d2_Wp=(const float*)d_in[17], *d2_bp=(const float*)d_in[18],
                *d2_Wl=(const float*)d_in[19], *d2_bl=(const float*)d_in[20],
                *d2_Wr=(const float*)d_in[21];

    // ---- workspace ----
    int* off  = (int*)d_ws;                     // N (persistent)
    int* csr  = off + N;                        // E (persistent)
    float* R1 = (float*)(csr + E);              // [N][128] layer output
    float* R2 = R1 + (size_t)N * 128;           // [N][128] scratch
    float* R3 = R2 + (size_t)N * 128;           // [N][64]  msgs / agg
    float* WT = R3 + (size_t)N * 64;            // transposed weights (~350 KB)
    // CSR-build temporaries alias R3 (done before R3's first float use)
    int* deg    = (int*)R3;
    int* cursor = deg + N;
    int* bsum   = cursor + N;

    // transposed-weight pointers
    float* t_e1Wp = WT;                 // 64x64   -> 4096
    float* t_e1Wl = t_e1Wp + 4096;      // [64][128]
    float* t_e1Wr = t_e1Wl + 8192;      // [64][128]
    float* t_e2Wr = t_e1Wr + 8192;      // [128][32]
    float* t_e2Wp = t_e2Wr + 4096;      // [128][128]
    float* t_e2Wl = t_e2Wp + 16384;     // [128][32]
    float* t_d1Wp = t_e2Wl + 4096;      // [32][32]
    float* t_d1Wl = t_d1Wp + 1024;      // [32][128]
    float* t_d1Wr = t_d1Wl + 4096;      // [32][128]
    float* t_d2Wr = t_d1Wr + 4096;      // [128][64]
    float* t_d2Wp = t_d2Wr + 8192;      // [128][128]
    float* t_d2Wl = t_d2Wp + 16384;     // [128][64]

    float* xrec = (float*)d_out;                // [N][64]
    float* z    = xrec + (size_t)N * 64;        // [N][32]

    const int GB = (N + 255) / 256;             // 391
    const int GT = (N + 127) / 128;             // 782

    // ---- weight transposes (inputs only; independent of CSR build) ----
    auto T = [&](const float* W, float* Wt, int M_, int K_) {
        int n = M_ * K_;
        transpose_w<<<(n + 255) / 256, 256, 0, stream>>>(W, Wt, M_, K_);
    };
    T(e1_Wp, t_e1Wp, 64, 64);
    T(e1_Wl, t_e1Wl, 128, 64);
    T(e1_Wr, t_e1Wr, 128, 64);
    T(e2_Wr, t_e2Wr, 32, 128);
    T(e2_Wp, t_e2Wp, 128, 128);
    T(e2_Wl, t_e2Wl, 32, 128);
    T(d1_Wp, t_d1Wp, 32, 32);
    T(d1_Wl, t_d1Wl, 128, 32);
    T(d1_Wr, t_d1Wr, 128, 32);
    T(d2_Wr, t_d2Wr, 64, 128);
    T(d2_Wp, t_d2Wp, 128, 128);
    T(d2_Wl, t_d2Wl, 64, 128);

    // ---- CSR build (once; shared by all 4 convs) ----
    hipMemsetAsync(deg, 0, N * sizeof(int), stream);
    hist_kernel<<<2048, 256, 0, stream>>>(ei, deg);
    scan_block<<<GB, 256, 0, stream>>>(deg, off, bsum);
    scan_bsum<<<1, 512, 0, stream>>>(bsum, GB);
    scan_add<<<GB, 256, 0, stream>>>(off, bsum, cursor);
    fill_kernel<<<2048, 256, 0, stream>>>(ei, cursor, csr);

    float* AP1 = R2;                    // conv1 messages [N][64]
    float* B1  = R2 + (size_t)N * 64;   // conv1 agg [N][64]
    float* AP2 = R3;                    // conv2/conv3 msgs [N][32]
    float* B3  = R3 + (size_t)N * 32;   // conv3 agg [N][32]
    float* AP4 = R3;                    // conv4 msgs [N][64]

    // ---- conv1 (e1): 64 -> 128, relu ----
    gemm_tile<64,64,true,false><<<GT, 256, 0, stream>>>(x, t_e1Wp, e1_bp, nullptr, nullptr, AP1);
    pull8<64,false><<<(N*8 + 255)/256, 256, 0, stream>>>(AP1, off, csr, B1);
    gemm_tile<64,128,true,true><<<GT, 256, 0, stream>>>(B1, t_e1Wl, e1_bl, x, t_e1Wr, R1);

    // ---- conv2 (e2): 128 -> 32 = z ----
    gemm_tile<128,32,false,false><<<GT, 256, 0, stream>>>(R1, t_e2Wr, e2_bl, nullptr, nullptr, z);
    gemm_tile<128,128,true,false><<<GT, 256, 0, stream>>>(R1, t_e2Wp, e2_bp, nullptr, nullptr, R2);
    gemm_tile<128,32,false,false><<<GT, 256, 0, stream>>>(R2, t_e2Wl, nullptr, nullptr, nullptr, AP2);
    pull8<32,true><<<(N*4 + 255)/256, 256, 0, stream>>>(AP2, off, csr, z);

    // ---- conv3 (d1): 32 -> 128, relu ----
    gemm_tile<32,32,true,false><<<GT, 256, 0, stream>>>(z, t_d1Wp, d1_bp, nullptr, nullptr, AP2);
    pull8<32,false><<<(N*4 + 255)/256, 256, 0, stream>>>(AP2, off, csr, B3);
    gemm_tile<32,128,true,true><<<GT, 256, 0, stream>>>(B3, t_d1Wl, d1_bl, z, t_d1Wr, R1);

    // ---- conv4 (d2): 128 -> 64 = x_rec ----
    gemm_tile<128,64,false,false><<<GT, 256, 0, stream>>>(R1, t_d2Wr, d2_bl, nullptr, nullptr, xrec);
    gemm_tile<128,128,true,false><<<GT, 256, 0, stream>>>(R1, t_d2Wp, d2_bp, nullptr, nullptr, R2);
    gemm_tile<128,64,false,false><<<GT, 256, 0, stream>>>(R2, t_d2Wl, nullptr, nullptr, nullptr, AP4);
    pull8<64,true><<<(N*8 + 255)/256, 256, 0, stream>>>(AP4, off, csr, xrec);
}

// Round 7
// 668.006 us; speedup vs baseline: 6.9172x; 1.0864x over previous
//
#include <hip/hip_runtime.h>

constexpr int N = 100000;
constexpr int E = 1600000;

// ---- bf16 helpers (RNE) ----
__device__ inline unsigned short f2bf(float x) {
    unsigned int b = __builtin_bit_cast(unsigned int, x);
    b = (b + 0x7FFFu + ((b >> 16) & 1u)) >> 16;
    return (unsigned short)b;
}
__device__ inline float bf2f(unsigned int u16) {
    unsigned int b = u16 << 16;
    return __builtin_bit_cast(float, b);
}

// ================= CSR build (dst-major) =================
__global__ __launch_bounds__(256) void hist_kernel(const int* __restrict__ ei,
                                                   int* __restrict__ deg) {
    for (int e = blockIdx.x * 256 + threadIdx.x; e < E; e += gridDim.x * 256)
        atomicAdd(&deg[ei[E + e]], 1);
}

__global__ __launch_bounds__(256) void scan_block(const int* __restrict__ deg,
                                                  int* __restrict__ off,
                                                  int* __restrict__ bsum) {
    __shared__ int tmp[256];
    int i = blockIdx.x * 256 + threadIdx.x;
    int v = (i < N) ? deg[i] : 0;
    tmp[threadIdx.x] = v;
    __syncthreads();
    for (int d = 1; d < 256; d <<= 1) {
        int t = (threadIdx.x >= d) ? tmp[threadIdx.x - d] : 0;
        __syncthreads();
        tmp[threadIdx.x] += t;
        __syncthreads();
    }
    if (i < N) off[i] = tmp[threadIdx.x] - v;
    if (threadIdx.x == 255) bsum[blockIdx.x] = tmp[255];
}

__global__ void scan_bsum(int* __restrict__ bsum, int nb) {
    __shared__ int tmp[512];
    int t = threadIdx.x;
    if (t < nb) tmp[t] = bsum[t];
    __syncthreads();
    if (t == 0) {
        int acc = 0;
        for (int b = 0; b < nb; ++b) { int x = tmp[b]; tmp[b] = acc; acc += x; }
    }
    __syncthreads();
    if (t < nb) bsum[t] = tmp[t];
}

__global__ __launch_bounds__(256) void scan_add(int* __restrict__ off,
                                                const int* __restrict__ bsum,
                                                int* __restrict__ cursor) {
    int i = blockIdx.x * 256 + threadIdx.x;
    if (i < N) { int v = off[i] + bsum[blockIdx.x]; off[i] = v; cursor[i] = v; }
}

__global__ __launch_bounds__(256) void fill_kernel(const int* __restrict__ ei,
                                                   int* __restrict__ cursor,
                                                   int* __restrict__ csr) {
    for (int e = blockIdx.x * 256 + threadIdx.x; e < E; e += gridDim.x * 256) {
        int pos = atomicAdd(&cursor[ei[E + e]], 1);
        csr[pos] = ei[e];
    }
}

// ================= batched weight transpose =================
struct TD {
    const float* s[12];
    float* d[12];
    int M[12];
    int K[12];
};
__global__ __launch_bounds__(256) void transpose_all(TD td) {
    int mi = blockIdx.y;
    const float* W = td.s[mi];
    float* Wt = td.d[mi];
    int M = td.M[mi], K = td.K[mi], n = M * K;
    for (int idx = blockIdx.x * 256 + threadIdx.x; idx < n; idx += gridDim.x * 256) {
        int m = idx / K, k = idx - m * K;
        Wt[k * M + m] = W[idx];
    }
}

// ================= pull aggregation over bf16 messages =================
// C/8 threads per node; each owns 8 bf16 (16B load), accumulates fp32,
// writes fp32 once. ADD: out[n] += agg (partial pre-written).
template<int C, bool ADD>
__global__ __launch_bounds__(256) void pull_bf(const unsigned short* __restrict__ feat,
                                               const int* __restrict__ off,
                                               const int* __restrict__ csr,
                                               float* __restrict__ out) {
    constexpr int TPN = C / 8;
    int t = blockIdx.x * 256 + threadIdx.x;
    int n = t / TPN, g = t % TPN;
    if (n >= N) return;
    int beg = off[n];
    int end = (n == N - 1) ? E : off[n + 1];
    float a[8];
    #pragma unroll
    for (int i = 0; i < 8; ++i) a[i] = 0.f;
    for (int j = beg; j < end; ++j) {
        int s = csr[j];
        uint4 v = *(const uint4*)(feat + (size_t)s * C + g * 8);
        a[0] += bf2f(v.x & 0xFFFFu); a[1] += bf2f(v.x >> 16);
        a[2] += bf2f(v.y & 0xFFFFu); a[3] += bf2f(v.y >> 16);
        a[4] += bf2f(v.z & 0xFFFFu); a[5] += bf2f(v.z >> 16);
        a[6] += bf2f(v.w & 0xFFFFu); a[7] += bf2f(v.w >> 16);
    }
    float* op = out + (size_t)n * C + g * 8;
    if (ADD) {
        float4 b0 = *(const float4*)op, b1 = *(const float4*)(op + 4);
        a[0] += b0.x; a[1] += b0.y; a[2] += b0.z; a[3] += b0.w;
        a[4] += b1.x; a[5] += b1.y; a[6] += b1.z; a[7] += b1.w;
    }
    *(float4*)op       = make_float4(a[0], a[1], a[2], a[3]);
    *(float4*)(op + 4) = make_float4(a[4], a[5], a[6], a[7]);
}

// ================= LDS-tiled GEMM =================
// out[row][:] = act( in[row]@Wt + bias (+ in2[row]@Wt2 if DUAL) ), Wt=[K][M].
// BM=128 rows/block, BK=32, 256 threads as 16x16, thread tile 8 x (M/16).
// OUTBF: epilogue packs to bf16 (message buffers). No uniformity assumptions.
template<int K, int M, bool RELU, bool DUAL, bool OUTBF>
__global__ __launch_bounds__(256) void gemm_tile(
    const float* __restrict__ in, const float* __restrict__ Wt,
    const float* __restrict__ bias,
    const float* __restrict__ in2, const float* __restrict__ Wt2,
    void* __restrict__ outv)
{
    constexpr int BM = 128, BK = 32;
    constexpr int TN  = M / 16;              // 8 / 4 / 2
    constexpr int KT1 = K / BK;
    constexpr int KT  = DUAL ? 2 * KT1 : KT1;
    constexpr int AST = BM + 4;
    constexpr int BST = M + 4;
    __shared__ float As[BK][AST];
    __shared__ float Bs[BK][BST];

    const int tx = threadIdx.x & 15;
    const int ty = threadIdx.x >> 4;
    const int row0 = blockIdx.x * BM;

    float acc[8][TN];
    #pragma unroll
    for (int i = 0; i < 8; ++i)
        #pragma unroll
        for (int j = 0; j < TN; ++j) acc[i][j] = 0.f;

    for (int kt = 0; kt < KT; ++kt) {
        const bool second = DUAL && (kt >= KT1);
        const float* src  = second ? in2 : in;
        const float* wsrc = second ? Wt2 : Wt;
        const int kbase = (second ? kt - KT1 : kt) * BK;

        #pragma unroll
        for (int it = 0; it < 4; ++it) {
            int idx = it * 256 + threadIdx.x;
            int r = idx >> 3, k4 = idx & 7;
            int rr = row0 + r;
            float4 v = {0.f,0.f,0.f,0.f};
            if (rr < N) v = *(const float4*)(src + (size_t)rr * K + kbase + k4 * 4);
            As[k4*4+0][r] = v.x;
            As[k4*4+1][r] = v.y;
            As[k4*4+2][r] = v.z;
            As[k4*4+3][r] = v.w;
        }
        constexpr int BIT = (BK * M / 4) / 256;
        #pragma unroll
        for (int it = 0; it < BIT; ++it) {
            int idx = it * 256 + threadIdx.x;
            int k = idx / (M / 4), m4 = idx % (M / 4);
            float4 v = *(const float4*)(wsrc + (size_t)(kbase + k) * M + m4 * 4);
            *(float4*)&Bs[k][m4 * 4] = v;
        }
        __syncthreads();

        #pragma unroll 4
        for (int kk = 0; kk < BK; ++kk) {
            float av[8];
            *(float4*)&av[0] = *(const float4*)&As[kk][ty * 8];
            *(float4*)&av[4] = *(const float4*)&As[kk][ty * 8 + 4];
            float bv[TN];
            if constexpr (TN == 8) {
                *(float4*)&bv[0] = *(const float4*)&Bs[kk][tx * 4];
                *(float4*)&bv[4] = *(const float4*)&Bs[kk][tx * 4 + 64];
            } else if constexpr (TN == 4) {
                *(float4*)&bv[0] = *(const float4*)&Bs[kk][tx * 4];
            } else {
                bv[0] = Bs[kk][tx * 2];
                bv[1] = Bs[kk][tx * 2 + 1];
            }
            #pragma unroll
            for (int i = 0; i < 8; ++i)
                #pragma unroll
                for (int j = 0; j < TN; ++j)
                    acc[i][j] = fmaf(av[i], bv[j], acc[i][j]);
        }
        __syncthreads();
    }

    // ---- epilogue ----
    float bb[TN];
    if (bias) {
        if constexpr (TN == 8) {
            *(float4*)&bb[0] = *(const float4*)(bias + tx * 4);
            *(float4*)&bb[4] = *(const float4*)(bias + tx * 4 + 64);
        } else if constexpr (TN == 4) {
            *(float4*)&bb[0] = *(const float4*)(bias + tx * 4);
        } else {
            bb[0] = bias[tx * 2]; bb[1] = bias[tx * 2 + 1];
        }
    } else {
        #pragma unroll
        for (int j = 0; j < TN; ++j) bb[j] = 0.f;
    }

    #pragma unroll
    for (int i = 0; i < 8; ++i) {
        int row = row0 + ty * 8 + i;
        if (row >= N) continue;
        float v[TN];
        #pragma unroll
        for (int j = 0; j < TN; ++j) {
            float s = acc[i][j] + bb[j];
            if (RELU) s = fmaxf(s, 0.f);
            v[j] = s;
        }
        if constexpr (!OUTBF) {
            float* op = (float*)outv + (size_t)row * M;
            if constexpr (TN == 8) {
                *(float4*)(op + tx * 4)      = make_float4(v[0], v[1], v[2], v[3]);
                *(float4*)(op + tx * 4 + 64) = make_float4(v[4], v[5], v[6], v[7]);
            } else if constexpr (TN == 4) {
                *(float4*)(op + tx * 4) = make_float4(v[0], v[1], v[2], v[3]);
            } else {
                *(float2*)(op + tx * 2) = make_float2(v[0], v[1]);
            }
        } else {
            unsigned short* op = (unsigned short*)outv + (size_t)row * M;
            if constexpr (TN == 8) {
                *(ushort4*)(op + tx * 4)      = make_ushort4(f2bf(v[0]), f2bf(v[1]), f2bf(v[2]), f2bf(v[3]));
                *(ushort4*)(op + tx * 4 + 64) = make_ushort4(f2bf(v[4]), f2bf(v[5]), f2bf(v[6]), f2bf(v[7]));
            } else if constexpr (TN == 4) {
                *(ushort4*)(op + tx * 4) = make_ushort4(f2bf(v[0]), f2bf(v[1]), f2bf(v[2]), f2bf(v[3]));
            } else {
                *(ushort2*)(op + tx * 2) = make_ushort2(f2bf(v[0]), f2bf(v[1]));
            }
        }
    }
}

extern "C" void kernel_launch(void* const* d_in, const int* in_sizes, int n_in,
                              void* d_out, int out_size, void* d_ws, size_t ws_size,
                              hipStream_t stream)
{
    const float* x   = (const float*)d_in[0];
    const int*   ei  = (const int*)d_in[1];
    const float *e1_Wp=(const float*)d_in[2],  *e1_bp=(const float*)d_in[3],
                *e1_Wl=(const float*)d_in[4],  *e1_bl=(const float*)d_in[5],
                *e1_Wr=(const float*)d_in[6];
    const float *e2_Wp=(const float*)d_in[7],  *e2_bp=(const float*)d_in[8],
                *e2_Wl=(const float*)d_in[9],  *e2_bl=(const float*)d_in[10],
                *e2_Wr=(const float*)d_in[11];
    const float *d1_Wp=(const float*)d_in[12], *d1_bp=(const float*)d_in[13],
                *d1_Wl=(const float*)d_in[14], *d1_bl=(const float*)d_in[15],
                *d1_Wr=(const float*)d_in[16];
    const float *d2_Wp=(const float*)d_in[17], *d2_bp=(const float*)d_in[18],
                *d2_Wl=(const float*)d_in[19], *d2_bl=(const float*)d_in[20],
                *d2_Wr=(const float*)d_in[21];

    // ---- workspace ----
    int* off  = (int*)d_ws;                     // N (persistent)
    int* csr  = off + N;                        // E (persistent)
    float* R1 = (float*)(csr + E);              // [N][128] layer output
    float* R2 = R1 + (size_t)N * 128;           // [N][128] scratch
    float* R3 = R2 + (size_t)N * 128;           // [N][64]  msgs / agg
    float* WT = R3 + (size_t)N * 64;            // transposed weights
    // CSR-build temporaries alias R3 (done before R3's first float use)
    int* deg    = (int*)R3;
    int* cursor = deg + N;
    int* bsum   = cursor + N;

    float* t_e1Wp = WT;
    float* t_e1Wl = t_e1Wp + 4096;
    float* t_e1Wr = t_e1Wl + 8192;
    float* t_e2Wr = t_e1Wr + 8192;
    float* t_e2Wp = t_e2Wr + 4096;
    float* t_e2Wl = t_e2Wp + 16384;
    float* t_d1Wp = t_e2Wl + 4096;
    float* t_d1Wl = t_d1Wp + 1024;
    float* t_d1Wr = t_d1Wl + 4096;
    float* t_d2Wr = t_d1Wr + 4096;
    float* t_d2Wp = t_d2Wr + 8192;
    float* t_d2Wl = t_d2Wp + 16384;

    float* xrec = (float*)d_out;                // [N][64]
    float* z    = xrec + (size_t)N * 64;        // [N][32]

    const int GB = (N + 255) / 256;             // 391
    const int GT = (N + 127) / 128;             // 782

    // ---- batched weight transposes (one kernel) ----
    TD td;
    const float* srcs[12] = {e1_Wp, e1_Wl, e1_Wr, e2_Wr, e2_Wp, e2_Wl,
                             d1_Wp, d1_Wl, d1_Wr, d2_Wr, d2_Wp, d2_Wl};
    float* dsts[12] = {t_e1Wp, t_e1Wl, t_e1Wr, t_e2Wr, t_e2Wp, t_e2Wl,
                       t_d1Wp, t_d1Wl, t_d1Wr, t_d2Wr, t_d2Wp, t_d2Wl};
    int Ms[12] = {64, 128, 128, 32, 128, 32, 32, 128, 128, 64, 128, 64};
    int Ks[12] = {64, 64, 64, 128, 128, 128, 32, 32, 32, 128, 128, 128};
    for (int i = 0; i < 12; ++i) {
        td.s[i] = srcs[i]; td.d[i] = dsts[i]; td.M[i] = Ms[i]; td.K[i] = Ks[i];
    }
    transpose_all<<<dim3(64, 12), 256, 0, stream>>>(td);

    // ---- CSR build ----
    hipMemsetAsync(deg, 0, N * sizeof(int), stream);
    hist_kernel<<<2048, 256, 0, stream>>>(ei, deg);
    scan_block<<<GB, 256, 0, stream>>>(deg, off, bsum);
    scan_bsum<<<1, 512, 0, stream>>>(bsum, GB);
    scan_add<<<GB, 256, 0, stream>>>(off, bsum, cursor);
    fill_kernel<<<2048, 256, 0, stream>>>(ei, cursor, csr);

    // bf16 message buffers (alias float regions; msgs written before aliased agg use)
    unsigned short* AP1bf = (unsigned short*)R2;          // [N][64] bf16
    float* B1  = R2 + (size_t)N * 64;                     // conv1 agg fp32 [N][64]
    unsigned short* AP2bf = (unsigned short*)R3;          // [N][32] bf16
    float* B3  = R3 + (size_t)N * 32;                     // conv3 agg fp32 [N][32]
    unsigned short* AP4bf = (unsigned short*)R3;          // [N][64] bf16

    // ---- conv1 (e1): 64 -> 128, relu ----
    gemm_tile<64,64,true,false,true><<<GT, 256, 0, stream>>>(x, t_e1Wp, e1_bp, nullptr, nullptr, AP1bf);
    pull_bf<64,false><<<(N*8 + 255)/256, 256, 0, stream>>>(AP1bf, off, csr, B1);
    gemm_tile<64,128,true,true,false><<<GT, 256, 0, stream>>>(B1, t_e1Wl, e1_bl, x, t_e1Wr, R1);

    // ---- conv2 (e2): 128 -> 32 = z ----
    gemm_tile<128,32,false,false,false><<<GT, 256, 0, stream>>>(R1, t_e2Wr, e2_bl, nullptr, nullptr, z);
    gemm_tile<128,128,true,false,false><<<GT, 256, 0, stream>>>(R1, t_e2Wp, e2_bp, nullptr, nullptr, R2);
    gemm_tile<128,32,false,false,true><<<GT, 256, 0, stream>>>(R2, t_e2Wl, nullptr, nullptr, nullptr, AP2bf);
    pull_bf<32,true><<<(N*4 + 255)/256, 256, 0, stream>>>(AP2bf, off, csr, z);

    // ---- conv3 (d1): 32 -> 128, relu ----
    gemm_tile<32,32,true,false,true><<<GT, 256, 0, stream>>>(z, t_d1Wp, d1_bp, nullptr, nullptr, AP2bf);
    pull_bf<32,false><<<(N*4 + 255)/256, 256, 0, stream>>>(AP2bf, off, csr, B3);
    gemm_tile<32,128,true,true,false><<<GT, 256, 0, stream>>>(B3, t_d1Wl, d1_bl, z, t_d1Wr, R1);

    // ---- conv4 (d2): 128 -> 64 = x_rec ----
    gemm_tile<128,64,false,false,false><<<GT, 256, 0, stream>>>(R1, t_d2Wr, d2_bl, nullptr, nullptr, xrec);
    gemm_tile<128,128,true,false,false><<<GT, 256, 0, stream>>>(R1, t_d2Wp, d2_bp, nullptr, nullptr, R2);
    gemm_tile<128,64,false,false,true><<<GT, 256, 0, stream>>>(R2, t_d2Wl, nullptr, nullptr, nullptr, AP4bf);
    pull_bf<64,true><<<(N*8 + 255)/256, 256, 0, stream>>>(AP4bf, off, csr, xrec);
}

// Round 8
// 527.267 us; speedup vs baseline: 8.7636x; 1.2669x over previous
//
#include <hip/hip_runtime.h>

constexpr int N = 100000;
constexpr int E = 1600000;

using bf16x8 = __attribute__((ext_vector_type(8))) short;
using f32x4  = __attribute__((ext_vector_type(4))) float;

__device__ inline unsigned short f2bf(float x) {
    unsigned int b = __builtin_bit_cast(unsigned int, x);
    b = (b + 0x7FFFu + ((b >> 16) & 1u)) >> 16;
    return (unsigned short)b;
}
__device__ inline float bf2f(unsigned int u) {
    unsigned int b = u << 16;
    return __builtin_bit_cast(float, b);
}

// ================= CSR build (dst-major) =================
__global__ __launch_bounds__(256) void hist_kernel(const int* __restrict__ ei,
                                                   int* __restrict__ deg) {
    for (int e = blockIdx.x * 256 + threadIdx.x; e < E; e += gridDim.x * 256)
        atomicAdd(&deg[ei[E + e]], 1);
}

__global__ __launch_bounds__(256) void scan_block(const int* __restrict__ deg,
                                                  int* __restrict__ off,
                                                  int* __restrict__ bsum) {
    __shared__ int tmp[256];
    int i = blockIdx.x * 256 + threadIdx.x;
    int v = (i < N) ? deg[i] : 0;
    tmp[threadIdx.x] = v;
    __syncthreads();
    for (int d = 1; d < 256; d <<= 1) {
        int t = (threadIdx.x >= d) ? tmp[threadIdx.x - d] : 0;
        __syncthreads();
        tmp[threadIdx.x] += t;
        __syncthreads();
    }
    if (i < N) off[i] = tmp[threadIdx.x] - v;
    if (threadIdx.x == 255) bsum[blockIdx.x] = tmp[255];
}

__global__ void scan_bsum(int* __restrict__ bsum, int nb) {
    __shared__ int tmp[512];
    int t = threadIdx.x;
    if (t < nb) tmp[t] = bsum[t];
    __syncthreads();
    if (t == 0) {
        int acc = 0;
        for (int b = 0; b < nb; ++b) { int x = tmp[b]; tmp[b] = acc; acc += x; }
    }
    __syncthreads();
    if (t < nb) bsum[t] = tmp[t];
}

__global__ __launch_bounds__(256) void scan_add(int* __restrict__ off,
                                                const int* __restrict__ bsum,
                                                int* __restrict__ cursor) {
    int i = blockIdx.x * 256 + threadIdx.x;
    if (i < N) { int v = off[i] + bsum[blockIdx.x]; off[i] = v; cursor[i] = v; }
}

__global__ __launch_bounds__(256) void fill_kernel(const int* __restrict__ ei,
                                                   int* __restrict__ cursor,
                                                   int* __restrict__ csr) {
    for (int e = blockIdx.x * 256 + threadIdx.x; e < E; e += gridDim.x * 256) {
        int pos = atomicAdd(&cursor[ei[E + e]], 1);
        csr[pos] = ei[e];
    }
}

// ================= fp32 -> bf16 converts =================
__global__ __launch_bounds__(256) void conv_x8(const float* __restrict__ in,
                                               unsigned short* __restrict__ out,
                                               int n8) {
    int i = blockIdx.x * 256 + threadIdx.x;
    if (i >= n8) return;
    const float* p = in + (size_t)i * 8;
    float4 v0 = *(const float4*)p;
    float4 v1 = *(const float4*)(p + 4);
    uint4 o;
    o.x = (unsigned)f2bf(v0.x) | ((unsigned)f2bf(v0.y) << 16);
    o.y = (unsigned)f2bf(v0.z) | ((unsigned)f2bf(v0.w) << 16);
    o.z = (unsigned)f2bf(v1.x) | ((unsigned)f2bf(v1.y) << 16);
    o.w = (unsigned)f2bf(v1.z) | ((unsigned)f2bf(v1.w) << 16);
    *(uint4*)(out + (size_t)i * 8) = o;
}

struct WC {
    const float* s[12];
    unsigned short* d[12];
    int n[12];
};
__global__ __launch_bounds__(256) void conv_w(WC wc) {
    int mi = blockIdx.y;
    const float* s = wc.s[mi];
    unsigned short* d = wc.d[mi];
    int n = wc.n[mi];
    for (int i = blockIdx.x * 256 + threadIdx.x; i < n; i += gridDim.x * 256)
        d[i] = f2bf(s[i]);
}

// ================= pull aggregation over bf16 messages =================
// MODE 0: write bf16 agg only. MODE 1: fp32 add into outf. MODE 2: fp32 add + bf16 mirror.
template<int C, int MODE>
__global__ __launch_bounds__(256) void pull_bf(const unsigned short* __restrict__ feat,
                                               const int* __restrict__ off,
                                               const int* __restrict__ csr,
                                               float* __restrict__ outf,
                                               unsigned short* __restrict__ outb) {
    constexpr int TPN = C / 8;
    int t = blockIdx.x * 256 + threadIdx.x;
    int n = t / TPN, g = t % TPN;
    if (n >= N) return;
    int beg = off[n];
    int end = (n == N - 1) ? E : off[n + 1];
    float a[8];
    #pragma unroll
    for (int i = 0; i < 8; ++i) a[i] = 0.f;
    for (int j = beg; j < end; ++j) {
        int s = csr[j];
        uint4 v = *(const uint4*)(feat + (size_t)s * C + g * 8);
        a[0] += bf2f(v.x & 0xFFFFu); a[1] += bf2f(v.x >> 16);
        a[2] += bf2f(v.y & 0xFFFFu); a[3] += bf2f(v.y >> 16);
        a[4] += bf2f(v.z & 0xFFFFu); a[5] += bf2f(v.z >> 16);
        a[6] += bf2f(v.w & 0xFFFFu); a[7] += bf2f(v.w >> 16);
    }
    if (MODE >= 1) {
        float* op = outf + (size_t)n * C + g * 8;
        float4 b0 = *(const float4*)op, b1 = *(const float4*)(op + 4);
        a[0] += b0.x; a[1] += b0.y; a[2] += b0.z; a[3] += b0.w;
        a[4] += b1.x; a[5] += b1.y; a[6] += b1.z; a[7] += b1.w;
        *(float4*)op       = make_float4(a[0], a[1], a[2], a[3]);
        *(float4*)(op + 4) = make_float4(a[4], a[5], a[6], a[7]);
    }
    if (MODE != 1) {
        uint4 o;
        o.x = (unsigned)f2bf(a[0]) | ((unsigned)f2bf(a[1]) << 16);
        o.y = (unsigned)f2bf(a[2]) | ((unsigned)f2bf(a[3]) << 16);
        o.z = (unsigned)f2bf(a[4]) | ((unsigned)f2bf(a[5]) << 16);
        o.w = (unsigned)f2bf(a[6]) | ((unsigned)f2bf(a[7]) << 16);
        *(uint4*)(outb + (size_t)n * C + g * 8) = o;
    }
}

// ================= MFMA bf16 GEMM =================
// out[row][0..M) = act( in1[row]@W1^T (+ in2[row]@W2^T) + bias ), all bf16 in,
// fp32 accumulate. Block = 4 waves = 64 rows; wave w owns rows w*16..+15.
// A tile [64][KV] and B tile (= W, [M][KV] virtual concat) staged in LDS,
// stride KV+8 (2-way bank conflicts only). Fragments (m89/m97-verified):
// A/B: lane&15 = row/col, k = (lane>>4)*8 + j (contiguous 8 -> ds_read_b128);
// C/D: col = lane&15, row = (lane>>4)*4 + reg.
template<int K1, int K2, int M, bool RELU, bool OBF>
__global__ __launch_bounds__(256) void gemm_mfma(
    const unsigned short* __restrict__ in1, const unsigned short* __restrict__ W1,
    const unsigned short* __restrict__ in2, const unsigned short* __restrict__ W2,
    const float* __restrict__ bias, void* __restrict__ outv)
{
    constexpr int KV = K1 + K2;
    constexpr int SK = KV + 8;
    constexpr int NF = M / 16;
    __shared__ unsigned short As[64 * SK];
    __shared__ unsigned short Bs[M * SK];

    const int tid = threadIdx.x;
    const int row0 = blockIdx.x * 64;

    // ---- stage A (rows, virtual-K concat) ----
    constexpr int AV = 64 * (KV / 8);
    for (int idx = tid; idx < AV; idx += 256) {
        int r = idx / (KV / 8), c = (idx % (KV / 8)) * 8;
        int rr = row0 + r;
        uint4 v = {0u, 0u, 0u, 0u};
        if (rr < N) {
            if constexpr (K2 == 0) {
                v = *(const uint4*)(in1 + (size_t)rr * K1 + c);
            } else {
                v = (c < K1) ? *(const uint4*)(in1 + (size_t)rr * K1 + c)
                             : *(const uint4*)(in2 + (size_t)rr * K2 + (c - K1));
            }
        }
        *(uint4*)&As[r * SK + c] = v;
    }
    // ---- stage B (= W rows, virtual-K concat) ----
    constexpr int BV = M * (KV / 8);
    for (int idx = tid; idx < BV; idx += 256) {
        int m = idx / (KV / 8), c = (idx % (KV / 8)) * 8;
        uint4 v;
        if constexpr (K2 == 0) {
            v = *(const uint4*)(W1 + (size_t)m * K1 + c);
        } else {
            v = (c < K1) ? *(const uint4*)(W1 + (size_t)m * K1 + c)
                         : *(const uint4*)(W2 + (size_t)m * K2 + (c - K1));
        }
        *(uint4*)&Bs[m * SK + c] = v;
    }
    __syncthreads();

    const int lane = tid & 63;
    const int wv   = tid >> 6;        // wave id -> row group
    const int lrow = lane & 15;
    const int kg   = lane >> 4;

    f32x4 acc[NF];
    #pragma unroll
    for (int cf = 0; cf < NF; ++cf) acc[cf] = (f32x4){0.f, 0.f, 0.f, 0.f};

    #pragma unroll
    for (int k0 = 0; k0 < KV; k0 += 32) {
        bf16x8 a = *(const bf16x8*)&As[(wv * 16 + lrow) * SK + k0 + kg * 8];
        #pragma unroll
        for (int cf = 0; cf < NF; ++cf) {
            bf16x8 b = *(const bf16x8*)&Bs[(cf * 16 + lrow) * SK + k0 + kg * 8];
            acc[cf] = __builtin_amdgcn_mfma_f32_16x16x32_bf16(a, b, acc[cf], 0, 0, 0);
        }
    }

    // ---- epilogue: C/D layout col=lane&15, row=(lane>>4)*4+reg ----
    #pragma unroll
    for (int cf = 0; cf < NF; ++cf) {
        int col = cf * 16 + lrow;
        float bsv = bias ? bias[col] : 0.f;
        #pragma unroll
        for (int r = 0; r < 4; ++r) {
            int row = row0 + wv * 16 + kg * 4 + r;
            if (row < N) {
                float v = acc[cf][r] + bsv;
                if (RELU) v = fmaxf(v, 0.f);
                if constexpr (OBF)
                    ((unsigned short*)outv)[(size_t)row * M + col] = f2bf(v);
                else
                    ((float*)outv)[(size_t)row * M + col] = v;
            }
        }
    }
}

extern "C" void kernel_launch(void* const* d_in, const int* in_sizes, int n_in,
                              void* d_out, int out_size, void* d_ws, size_t ws_size,
                              hipStream_t stream)
{
    const float* x   = (const float*)d_in[0];
    const int*   ei  = (const int*)d_in[1];
    const float *e1_Wp=(const float*)d_in[2],  *e1_bp=(const float*)d_in[3],
                *e1_Wl=(const float*)d_in[4],  *e1_bl=(const float*)d_in[5],
                *e1_Wr=(const float*)d_in[6];
    const float *e2_Wp=(const float*)d_in[7],  *e2_bp=(const float*)d_in[8],
                *e2_Wl=(const float*)d_in[9],  *e2_bl=(const float*)d_in[10],
                *e2_Wr=(const float*)d_in[11];
    const float *d1_Wp=(const float*)d_in[12], *d1_bp=(const float*)d_in[13],
                *d1_Wl=(const float*)d_in[14], *d1_bl=(const float*)d_in[15],
                *d1_Wr=(const float*)d_in[16];
    const float *d2_Wp=(const float*)d_in[17], *d2_bp=(const float*)d_in[18],
                *d2_Wl=(const float*)d_in[19], *d2_bl=(const float*)d_in[20],
                *d2_Wr=(const float*)d_in[21];

    typedef unsigned short u16;

    // ---- workspace ----
    int* off  = (int*)d_ws;                       // N
    int* csr  = off + N;                          // E
    u16* xbf  = (u16*)(csr + E);                  // [N][64]
    u16* R1bf = xbf  + (size_t)N * 64;            // [N][128] layer feats
    u16* Hbf  = R1bf + (size_t)N * 128;           // [N][128] projected (scratch)
    u16* MSG  = Hbf  + (size_t)N * 128;           // [N][64] messages
    u16* AGG  = MSG  + (size_t)N * 64;            // [N][64] aggregates
    u16* zbf  = AGG  + (size_t)N * 64;            // [N][32]
    u16* WB   = zbf  + (size_t)N * 32;            // bf16 weights (~173 KB)
    // CSR-build temporaries alias Hbf (done before Hbf's first use)
    int* deg    = (int*)Hbf;
    int* cursor = deg + N;
    int* bsum   = cursor + N;

    u16* b_e1Wp = WB;                  // 64x64
    u16* b_e1Wl = b_e1Wp + 4096;       // 128x64
    u16* b_e1Wr = b_e1Wl + 8192;       // 128x64
    u16* b_e2Wr = b_e1Wr + 8192;       // 32x128
    u16* b_e2Wp = b_e2Wr + 4096;       // 128x128
    u16* b_e2Wl = b_e2Wp + 16384;      // 32x128
    u16* b_d1Wp = b_e2Wl + 4096;       // 32x32
    u16* b_d1Wl = b_d1Wp + 1024;       // 128x32
    u16* b_d1Wr = b_d1Wl + 4096;       // 128x32
    u16* b_d2Wr = b_d1Wr + 4096;       // 64x128
    u16* b_d2Wp = b_d2Wr + 8192;       // 128x128
    u16* b_d2Wl = b_d2Wp + 16384;      // 64x128

    float* xrec = (float*)d_out;                  // [N][64]
    float* z    = xrec + (size_t)N * 64;          // [N][32]

    const int GB = (N + 255) / 256;               // 391
    const int GM = (N + 63) / 64;                 // 1563 (mfma gemm grid)

    // ---- converts ----
    conv_x8<<<(N * 64 / 8 + 255) / 256, 256, 0, stream>>>(x, xbf, N * 64 / 8);
    WC wc;
    const float* ws_[12] = {e1_Wp, e1_Wl, e1_Wr, e2_Wr, e2_Wp, e2_Wl,
                            d1_Wp, d1_Wl, d1_Wr, d2_Wr, d2_Wp, d2_Wl};
    u16* wd_[12] = {b_e1Wp, b_e1Wl, b_e1Wr, b_e2Wr, b_e2Wp, b_e2Wl,
                    b_d1Wp, b_d1Wl, b_d1Wr, b_d2Wr, b_d2Wp, b_d2Wl};
    int wn_[12] = {4096, 8192, 8192, 4096, 16384, 4096,
                   1024, 4096, 4096, 8192, 16384, 8192};
    for (int i = 0; i < 12; ++i) { wc.s[i] = ws_[i]; wc.d[i] = wd_[i]; wc.n[i] = wn_[i]; }
    conv_w<<<dim3(64, 12), 256, 0, stream>>>(wc);

    // ---- CSR build ----
    hipMemsetAsync(deg, 0, N * sizeof(int), stream);
    hist_kernel<<<2048, 256, 0, stream>>>(ei, deg);
    scan_block<<<GB, 256, 0, stream>>>(deg, off, bsum);
    scan_bsum<<<1, 512, 0, stream>>>(bsum, GB);
    scan_add<<<GB, 256, 0, stream>>>(off, bsum, cursor);
    fill_kernel<<<2048, 256, 0, stream>>>(ei, cursor, csr);

    // ---- conv1 (e1): 64 -> 128, relu ----
    gemm_mfma<64,0,64,true,true><<<GM, 256, 0, stream>>>(xbf, b_e1Wp, nullptr, nullptr, e1_bp, MSG);
    pull_bf<64,0><<<(N*8 + 255)/256, 256, 0, stream>>>(MSG, off, csr, nullptr, AGG);
    gemm_mfma<64,64,128,true,true><<<GM, 256, 0, stream>>>(AGG, b_e1Wl, xbf, b_e1Wr, e1_bl, R1bf);

    // ---- conv2 (e2): 128 -> 32 = z ----
    gemm_mfma<128,0,32,false,false><<<GM, 256, 0, stream>>>(R1bf, b_e2Wr, nullptr, nullptr, e2_bl, z);
    gemm_mfma<128,0,128,true,true><<<GM, 256, 0, stream>>>(R1bf, b_e2Wp, nullptr, nullptr, e2_bp, Hbf);
    gemm_mfma<128,0,32,false,true><<<GM, 256, 0, stream>>>(Hbf, b_e2Wl, nullptr, nullptr, nullptr, MSG);
    pull_bf<32,2><<<(N*4 + 255)/256, 256, 0, stream>>>(MSG, off, csr, z, zbf);

    // ---- conv3 (d1): 32 -> 128, relu ----
    gemm_mfma<32,0,32,true,true><<<GM, 256, 0, stream>>>(zbf, b_d1Wp, nullptr, nullptr, d1_bp, MSG);
    pull_bf<32,0><<<(N*4 + 255)/256, 256, 0, stream>>>(MSG, off, csr, nullptr, AGG);
    gemm_mfma<32,32,128,true,true><<<GM, 256, 0, stream>>>(AGG, b_d1Wl, zbf, b_d1Wr, d1_bl, R1bf);

    // ---- conv4 (d2): 128 -> 64 = x_rec ----
    gemm_mfma<128,0,64,false,false><<<GM, 256, 0, stream>>>(R1bf, b_d2Wr, nullptr, nullptr, d2_bl, xrec);
    gemm_mfma<128,0,128,true,true><<<GM, 256, 0, stream>>>(R1bf, b_d2Wp, nullptr, nullptr, d2_bp, Hbf);
    gemm_mfma<128,0,64,false,true><<<GM, 256, 0, stream>>>(Hbf, b_d2Wl, nullptr, nullptr, nullptr, MSG);
    pull_bf<64,1><<<(N*8 + 255)/256, 256, 0, stream>>>(MSG, off, csr, xrec, nullptr);
}